// Round 9
// baseline (599.615 us; speedup 1.0000x reference)
//
#include <hip/hip_runtime.h>

typedef __attribute__((ext_vector_type(8))) short bf16x8;
typedef __attribute__((ext_vector_type(4))) float f32x4;
typedef __attribute__((ext_vector_type(2))) unsigned int u32x2;
typedef __attribute__((ext_vector_type(4))) unsigned int u32x4;

#define LOG2E  1.442695040888963f
#define LOG2E2 2.885390081777927f

__device__ __forceinline__ unsigned cvt_pk_bf16(float lo, float hi){
  unsigned r; asm("v_cvt_pk_bf16_f32 %0, %1, %2" : "=v"(r) : "v"(lo), "v"(hi)); return r;
}
__device__ __forceinline__ float sig_p(float z){          // z pre-scaled by log2e
  return __builtin_amdgcn_rcpf(1.f + __builtin_amdgcn_exp2f(-z));
}
__device__ __forceinline__ float tanhg_p(float z){        // z pre-scaled by 2*log2e
  return 1.f - 2.f*__builtin_amdgcn_rcpf(1.f + __builtin_amdgcn_exp2f(z));
}
__device__ __forceinline__ float tanh_f(float x){         // natural domain
  return 1.f - 2.f*__builtin_amdgcn_rcpf(1.f + __builtin_amdgcn_exp2f(LOG2E2*x));
}

// ---------------- prologue 1: embproj[dir][tok][m] = (emb[tok]@Wx + b) * gate_scale ------
__global__ void embproj_kernel(const float* __restrict__ emb,
                               const float* __restrict__ Wx_f, const float* __restrict__ b_f,
                               const float* __restrict__ Wx_b, const float* __restrict__ b_b,
                               float* __restrict__ embproj){
  const int blk = blockIdx.x;
  const int dir = blk >> 9;
  const int tok = (blk >> 2) & 127;
  const int m   = (blk & 3)*256 + threadIdx.x;
  const float* Wx = dir ? Wx_b : Wx_f;
  const float* bb = dir ? b_b  : b_f;
  __shared__ float es[128];
  if (threadIdx.x < 128) es[threadIdx.x] = emb[tok*128 + threadIdx.x];
  __syncthreads();
  float acc = bb[m];
  #pragma unroll 4
  for (int e = 0; e < 128; e++) acc = fmaf(es[e], Wx[e*1024 + m], acc);
  const float s = ((m >> 8) == 2) ? LOG2E2 : LOG2E;
  embproj[(dir*128 + tok)*1024 + m] = acc * s;
}

// ---------------- prologue 2: pack Wh^T into MFMA A-frag order (bf16), pre-scaled ---------
__global__ void whpack_kernel(const float* __restrict__ Wh_f, const float* __restrict__ Wh_b,
                              u32x4* __restrict__ whpack){
  const int t = blockIdx.x*256 + threadIdx.x;
  const int lane = t & 63;
  const int kb   = (t >> 6) & 7;
  const int mf   = (t >> 9) & 63;
  const int dir  = t >> 15;
  const float* Wh = dir ? Wh_b : Wh_f;
  const int m = mf*16 + (lane & 15);
  const int kbase = kb*32 + ((lane >> 4) << 2);
  const float s = ((mf >> 4) == 2) ? LOG2E2 : LOG2E;
  u32x4 o;
  #pragma unroll
  for (int p = 0; p < 4; p++){
    const int k0 = kbase + (p & 1)*2 + (p >> 1)*16;
    unsigned pk = cvt_pk_bf16(Wh[k0*1024 + m]*s, Wh[(k0+1)*1024 + m]*s);
    if (p == 0) o.x = pk; else if (p == 1) o.y = pk; else if (p == 2) o.z = pk; else o.w = pk;
  }
  whpack[t] = o;
}

// ---------------- main: persistent LSTM, MFMA/VALU phase-overlapped -----------------------
// grid 256 = 2 dir * 128 tiles of 16 batch rows. 512 thr = 8 waves (2/SIMD).
// Wave w, frag f=g*2+q -> mf = g*16+2w+q.  Weight sources (each kb consumed in BOTH phases):
//   kb0,1,2,4 resident (128 regs) | kb3,kb5 streamed windows W1,W2 (64 regs, refill in P3)
//   kb6,7 in LDS (128 KB), JIT
// Step: P1 = q0 MFMAs; P2 = q1 MFMAs source-interleaved with q0 gate elements (matrix pipe
// and VALU/trans pipe overlap); P3 = q1 gates + h write + refills + xz(t+1), then
// lgkmcnt-only barrier (global loads stay in flight).
__global__ __launch_bounds__(512, 2) void lstm_kernel(
    const int* __restrict__ tokens, const float* __restrict__ embproj,
    const u32x4* __restrict__ whpack, float* __restrict__ out)
{
  const int bid = blockIdx.x;
  const int dir = bid >> 7;
  const int r0  = (bid & 127) << 4;
  const int tid = threadIdx.x;
  const int w   = tid >> 6;
  const int l   = tid & 63;
  const int l15 = l & 15;
  const int lg  = l >> 4;

  const float* ep = embproj + dir*131072;
  const u32x4* wp = whpack + dir*32768;

  __shared__ __align__(16) unsigned hbuf[2][8][64][4];   // 16 KB h double-buffer (B-frag)
  __shared__ __align__(16) u32x4 wlds[8][8][2][64];      // 128 KB: [w][f][kb-6][lane]
  __shared__ int ts[16][132];

  for (int i = tid; i < 2048; i += 512)
    ts[i >> 7][i & 127] = tokens[(r0 + (i >> 7))*128 + (i & 127)];
  for (int i = tid; i < 4096; i += 512) (&hbuf[0][0][0][0])[i] = 0u;
  #pragma unroll
  for (int f = 0; f < 8; f++)
    #pragma unroll
    for (int kbh = 0; kbh < 2; kbh++)
      wlds[w][f][kbh][l] = wp[(((f >> 1)*16 + 2*w + (f & 1))*8 + 6 + kbh)*64 + l];

  // resident: kb0,1,2 (j=0..2) and kb4 (j=3) for all f  -> 32 frags = 128 regs
  bf16x8 Wr[8][4];
  #pragma unroll
  for (int f = 0; f < 8; f++){
    #pragma unroll
    for (int j = 0; j < 3; j++)
      Wr[f][j] = *(const bf16x8*)&wp[(((f >> 1)*16 + 2*w + (f & 1))*8 + j)*64 + l];
    Wr[f][3] = *(const bf16x8*)&wp[(((f >> 1)*16 + 2*w + (f & 1))*8 + 4)*64 + l];
  }
  __syncthreads();

  f32x4 c4[2] = {{0.f,0.f,0.f,0.f},{0.f,0.f,0.f,0.f}};

  // prologue: xz(0) -> acc; stream windows W1<-kb3, W2<-kb5
  f32x4 acc[8];
  {
    const int tok0 = ts[l15][dir ? 127 : 0];
    const float* gp = ep + tok0*1024 + 32*w + lg*4;
    #pragma unroll
    for (int f = 0; f < 8; f++)
      acc[f] = *(const f32x4*)(gp + (f >> 1)*256 + (f & 1)*16);
  }
  bf16x8 W1[8], W2[8];
  #pragma unroll
  for (int f = 0; f < 8; f++){
    W1[f] = *(const bf16x8*)&wp[(((f >> 1)*16 + 2*w + (f & 1))*8 + 3)*64 + l];
    W2[f] = *(const bf16x8*)&wp[(((f >> 1)*16 + 2*w + (f & 1))*8 + 5)*64 + l];
  }

#define MFMA4(Q, A0, A1, A2, A3, BB) \
  acc[0+(Q)] = __builtin_amdgcn_mfma_f32_16x16x32_bf16(A0, BB, acc[0+(Q)], 0,0,0); \
  acc[2+(Q)] = __builtin_amdgcn_mfma_f32_16x16x32_bf16(A1, BB, acc[2+(Q)], 0,0,0); \
  acc[4+(Q)] = __builtin_amdgcn_mfma_f32_16x16x32_bf16(A2, BB, acc[4+(Q)], 0,0,0); \
  acc[6+(Q)] = __builtin_amdgcn_mfma_f32_16x16x32_bf16(A3, BB, acc[6+(Q)], 0,0,0);

#define GATE_ELEM(Q, R, HN) { \
  const float cc = sig_p(acc[2+(Q)][R])*c4[Q][R] + sig_p(acc[0+(Q)][R])*tanhg_p(acc[4+(Q)][R]); \
  c4[Q][R] = cc; \
  HN[R] = sig_p(acc[6+(Q)][R])*tanh_f(cc); }

  f32x4 hn0, hn1;

  for (int t = 0; t < 128; t++){
    const int tn    = (t < 127) ? t + 1 : 127;
    const int tok_n = ts[l15][dir ? (127 - tn) : tn];
    const int rb = t & 1;

    // ---------------- P1: q=0 MFMAs (even f), B JIT-rolled ----------------
    {
      bf16x8 Ba = *(const bf16x8*)&hbuf[rb][0][l][0];
      bf16x8 Bb = *(const bf16x8*)&hbuf[rb][1][l][0];
      MFMA4(0, Wr[0][0], Wr[2][0], Wr[4][0], Wr[6][0], Ba);
      Ba = *(const bf16x8*)&hbuf[rb][2][l][0];
      MFMA4(0, Wr[0][1], Wr[2][1], Wr[4][1], Wr[6][1], Bb);
      Bb = *(const bf16x8*)&hbuf[rb][3][l][0];
      MFMA4(0, Wr[0][2], Wr[2][2], Wr[4][2], Wr[6][2], Ba);
      Ba = *(const bf16x8*)&hbuf[rb][4][l][0];
      MFMA4(0, W1[0], W1[2], W1[4], W1[6], Bb);             // kb3
      Bb = *(const bf16x8*)&hbuf[rb][5][l][0];
      MFMA4(0, Wr[0][3], Wr[2][3], Wr[4][3], Wr[6][3], Ba); // kb4
      Ba = *(const bf16x8*)&hbuf[rb][6][l][0];
      bf16x8 Wl0 = *(const bf16x8*)&wlds[w][0][0][l];
      bf16x8 Wl1 = *(const bf16x8*)&wlds[w][2][0][l];
      bf16x8 Wl2 = *(const bf16x8*)&wlds[w][4][0][l];
      bf16x8 Wl3 = *(const bf16x8*)&wlds[w][6][0][l];
      MFMA4(0, W2[0], W2[2], W2[4], W2[6], Bb);             // kb5
      Bb = *(const bf16x8*)&hbuf[rb][7][l][0];
      MFMA4(0, Wl0, Wl1, Wl2, Wl3, Ba);                     // kb6
      Wl0 = *(const bf16x8*)&wlds[w][0][1][l];
      Wl1 = *(const bf16x8*)&wlds[w][2][1][l];
      Wl2 = *(const bf16x8*)&wlds[w][4][1][l];
      Wl3 = *(const bf16x8*)&wlds[w][6][1][l];
      MFMA4(0, Wl0, Wl1, Wl2, Wl3, Bb);                     // kb7
    }

    // ------- P2: q=1 MFMAs interleaved with q=0 gate elements (pipe overlap) -------
    {
      bf16x8 Ba = *(const bf16x8*)&hbuf[rb][0][l][0];
      bf16x8 Bb = *(const bf16x8*)&hbuf[rb][1][l][0];
      MFMA4(1, Wr[1][0], Wr[3][0], Wr[5][0], Wr[7][0], Ba);
      Ba = *(const bf16x8*)&hbuf[rb][2][l][0];
      MFMA4(1, Wr[1][1], Wr[3][1], Wr[5][1], Wr[7][1], Bb);
      GATE_ELEM(0, 0, hn0);
      Bb = *(const bf16x8*)&hbuf[rb][3][l][0];
      MFMA4(1, Wr[1][2], Wr[3][2], Wr[5][2], Wr[7][2], Ba);
      Ba = *(const bf16x8*)&hbuf[rb][4][l][0];
      MFMA4(1, W1[1], W1[3], W1[5], W1[7], Bb);             // kb3
      GATE_ELEM(0, 1, hn0);
      Bb = *(const bf16x8*)&hbuf[rb][5][l][0];
      MFMA4(1, Wr[1][3], Wr[3][3], Wr[5][3], Wr[7][3], Ba); // kb4
      Ba = *(const bf16x8*)&hbuf[rb][6][l][0];
      bf16x8 Wl0 = *(const bf16x8*)&wlds[w][1][0][l];
      bf16x8 Wl1 = *(const bf16x8*)&wlds[w][3][0][l];
      bf16x8 Wl2 = *(const bf16x8*)&wlds[w][5][0][l];
      bf16x8 Wl3 = *(const bf16x8*)&wlds[w][7][0][l];
      MFMA4(1, W2[1], W2[3], W2[5], W2[7], Bb);             // kb5
      GATE_ELEM(0, 2, hn0);
      Bb = *(const bf16x8*)&hbuf[rb][7][l][0];
      MFMA4(1, Wl0, Wl1, Wl2, Wl3, Ba);                     // kb6
      Wl0 = *(const bf16x8*)&wlds[w][1][1][l];
      Wl1 = *(const bf16x8*)&wlds[w][3][1][l];
      Wl2 = *(const bf16x8*)&wlds[w][5][1][l];
      Wl3 = *(const bf16x8*)&wlds[w][7][1][l];
      GATE_ELEM(0, 3, hn0);
      MFMA4(1, Wl0, Wl1, Wl2, Wl3, Bb);                     // kb7
    }

    // ---------------- P3: q=1 gates, h write, refills, xz(t+1) ----------------
    GATE_ELEM(1, 0, hn1);
    GATE_ELEM(1, 1, hn1);
    GATE_ELEM(1, 2, hn1);
    GATE_ELEM(1, 3, hn1);

    u32x4 pk;
    pk.x = cvt_pk_bf16(hn0[0], hn0[1]);
    pk.y = cvt_pk_bf16(hn0[2], hn0[3]);
    pk.z = cvt_pk_bf16(hn1[0], hn1[1]);
    pk.w = cvt_pk_bf16(hn1[2], hn1[3]);

    if (t == 127){
      const int b = r0 + l15;
      const int u0 = 32*w + lg*4;
      *(f32x4*)(out + b*512 + dir*256 + u0)                    = hn0;
      *(f32x4*)(out + b*512 + dir*256 + u0 + 16)               = hn1;
      *(f32x4*)(out + 1048576 + dir*1048576 + b*256 + u0)      = hn0;
      *(f32x4*)(out + 1048576 + dir*1048576 + b*256 + u0 + 16) = hn1;
    }
    *(u32x4*)&hbuf[rb ^ 1][w][l][0] = pk;

    // stream refills for next step (stay in flight across the barrier)
    #pragma unroll
    for (int f = 0; f < 8; f++){
      W1[f] = *(const bf16x8*)&wp[(((f >> 1)*16 + 2*w + (f & 1))*8 + 3)*64 + l];
      W2[f] = *(const bf16x8*)&wp[(((f >> 1)*16 + 2*w + (f & 1))*8 + 5)*64 + l];
    }
    // xz(t+1) -> acc C-init
    const float* gpn = ep + tok_n*1024 + 32*w + lg*4;
    #pragma unroll
    for (int f = 0; f < 8; f++)
      acc[f] = *(const f32x4*)(gpn + (f >> 1)*256 + (f & 1)*16);

    asm volatile("s_waitcnt lgkmcnt(0)" ::: "memory");
    __builtin_amdgcn_s_barrier();
    __builtin_amdgcn_sched_barrier(0);
  }

  #pragma unroll
  for (int q = 0; q < 2; q++){
    const int b  = r0 + l15;
    const int u0 = 32*w + 16*q + lg*4;
    *(f32x4*)(out + 1572864 + dir*1048576 + b*256 + u0) = c4[q];
  }
#undef MFMA4
#undef GATE_ELEM
}

extern "C" void kernel_launch(void* const* d_in, const int* in_sizes, int n_in,
                              void* d_out, int out_size, void* d_ws, size_t ws_size,
                              hipStream_t stream){
  const int*   tokens = (const int*)  d_in[0];
  const float* emb    = (const float*)d_in[1];
  const float* Wx_f   = (const float*)d_in[2];
  const float* Wh_f   = (const float*)d_in[3];
  const float* b_f    = (const float*)d_in[4];
  const float* Wx_b   = (const float*)d_in[5];
  const float* Wh_b   = (const float*)d_in[6];
  const float* b_b    = (const float*)d_in[7];
  float* out = (float*)d_out;

  float*  embproj = (float*)d_ws;
  u32x4*  whpack  = (u32x4*)(embproj + 262144);

  embproj_kernel<<<1024, 256, 0, stream>>>(emb, Wx_f, b_f, Wx_b, b_b, embproj);
  whpack_kernel<<<256, 256, 0, stream>>>(Wh_f, Wh_b, whpack);
  lstm_kernel<<<256, 512, 0, stream>>>(tokens, embproj, whpack, out);
}

// Round 10
// 482.074 us; speedup vs baseline: 1.2438x; 1.2438x over previous
//
#include <hip/hip_runtime.h>

typedef __attribute__((ext_vector_type(8))) short bf16x8;
typedef __attribute__((ext_vector_type(4))) float f32x4;
typedef __attribute__((ext_vector_type(2))) unsigned int u32x2;
typedef __attribute__((ext_vector_type(4))) unsigned int u32x4;

#define LOG2E  1.442695040888963f
#define LOG2E2 2.885390081777927f

__device__ __forceinline__ unsigned cvt_pk_bf16(float lo, float hi){
  unsigned r; asm("v_cvt_pk_bf16_f32 %0, %1, %2" : "=v"(r) : "v"(lo), "v"(hi)); return r;
}

// ---------------- prologue 1: embproj[dir][tok][m] = (emb[tok]@Wx + b) * gate_scale ------
__global__ void embproj_kernel(const float* __restrict__ emb,
                               const float* __restrict__ Wx_f, const float* __restrict__ b_f,
                               const float* __restrict__ Wx_b, const float* __restrict__ b_b,
                               float* __restrict__ embproj){
  const int blk = blockIdx.x;
  const int dir = blk >> 9;
  const int tok = (blk >> 2) & 127;
  const int m   = (blk & 3)*256 + threadIdx.x;
  const float* Wx = dir ? Wx_b : Wx_f;
  const float* bb = dir ? b_b  : b_f;
  __shared__ float es[128];
  if (threadIdx.x < 128) es[threadIdx.x] = emb[tok*128 + threadIdx.x];
  __syncthreads();
  float acc = bb[m];
  #pragma unroll 4
  for (int e = 0; e < 128; e++) acc = fmaf(es[e], Wx[e*1024 + m], acc);
  const float s = ((m >> 8) == 2) ? LOG2E2 : LOG2E;
  embproj[(dir*128 + tok)*1024 + m] = acc * s;
}

// ---------------- prologue 2: pack Wh^T into MFMA A-frag order (bf16), pre-scaled ---------
// frag layout: [dir][mf(64)][kb(8)][lane(64)] x 16B; m = mf*16+(l&15),
// k-slot j: k = kb*32 + (l>>4)*4 + (j&3) + 16*(j>>2)   (A and B share the map)
__global__ void whpack_kernel(const float* __restrict__ Wh_f, const float* __restrict__ Wh_b,
                              u32x4* __restrict__ whpack){
  const int t = blockIdx.x*256 + threadIdx.x;
  const int lane = t & 63;
  const int kb   = (t >> 6) & 7;
  const int mf   = (t >> 9) & 63;
  const int dir  = t >> 15;
  const float* Wh = dir ? Wh_b : Wh_f;
  const int m = mf*16 + (lane & 15);
  const int kbase = kb*32 + ((lane >> 4) << 2);
  const float s = ((mf >> 4) == 2) ? LOG2E2 : LOG2E;
  u32x4 o;
  #pragma unroll
  for (int p = 0; p < 4; p++){
    const int k0 = kbase + (p & 1)*2 + (p >> 1)*16;
    unsigned pk = cvt_pk_bf16(Wh[k0*1024 + m]*s, Wh[(k0+1)*1024 + m]*s);
    if (p == 0) o.x = pk; else if (p == 1) o.y = pk; else if (p == 2) o.z = pk; else o.w = pk;
  }
  whpack[t] = o;
}

// ---------------- prologue 3: repack streamed frags (kb3,kb5) contiguous per wave ---------
// wstream[dir][w][s(2)][f(8)][lane] : loop-invariant base + const offsets in main loop.
__global__ void wstream_kernel(const u32x4* __restrict__ whpack, u32x4* __restrict__ wstream){
  const int t = blockIdx.x*256 + threadIdx.x;   // 16384
  const int lane = t & 63;
  const int f    = (t >> 6) & 7;
  const int s    = (t >> 9) & 1;
  const int w    = (t >> 10) & 7;
  const int dir  = t >> 13;
  const int mf = (f >> 1)*16 + 2*w + (f & 1);
  const int kb = s ? 5 : 3;
  wstream[t] = whpack[dir*32768 + (mf*8 + kb)*64 + lane];
}

// ---------------- main: persistent LSTM ---------------------------------------------------
// grid 256 = 2 dir * 128 tiles of 16 batch rows. 512 thr = 8 waves (2/SIMD).
// Wave w, frag f=g*2+q -> mf=(f>>1)*16+2w+(f&1).
//   kb0,1,2,4 resident (128 regs) | kb3,kb5 via ONE streamed window Wg (32 regs,
//   contiguous wstream addresses) | kb6,7 in LDS, ONE 4-frag JIT window.
// setprio(1) wraps the MFMA region: an MFMA-phase wave preempts its gate-phase co-wave
// (cross-wave MFMA/VALU overlap — the r9 in-wave interleave was the wrong mechanism).
// Barrier drains lgkm only; global loads (Wg refill, xz) stay in flight across it.
__global__ __launch_bounds__(512, 2) void lstm_kernel(
    const int* __restrict__ tokens, const float* __restrict__ embproj,
    const u32x4* __restrict__ whpack, const u32x4* __restrict__ wstream,
    float* __restrict__ out)
{
  const int bid = blockIdx.x;
  const int dir = bid >> 7;
  const int r0  = (bid & 127) << 4;
  const int tid = threadIdx.x;
  const int w   = tid >> 6;
  const int l   = tid & 63;
  const int l15 = l & 15;
  const int lg  = l >> 4;

  const float* ep  = embproj + dir*131072;
  const u32x4* wp  = whpack + dir*32768;
  const u32x4* wsb = wstream + ((dir*8 + w)*16)*64 + l;   // loop-invariant stream base

  __shared__ __align__(16) unsigned hbuf[2][8][64][4];   // 16 KB h double-buffer (B-frag)
  __shared__ __align__(16) u32x4 wlds[8][8][2][64];      // 128 KB: [w][f][kb-6][lane]
  __shared__ int ts[16][132];

  for (int i = tid; i < 2048; i += 512)
    ts[i >> 7][i & 127] = tokens[(r0 + (i >> 7))*128 + (i & 127)];
  for (int i = tid; i < 4096; i += 512) (&hbuf[0][0][0][0])[i] = 0u;
  #pragma unroll
  for (int f = 0; f < 8; f++)
    #pragma unroll
    for (int kbh = 0; kbh < 2; kbh++)
      wlds[w][f][kbh][l] = wp[(((f >> 1)*16 + 2*w + (f & 1))*8 + 6 + kbh)*64 + l];

  // resident: kb0,1,2 (j=0..2), kb4 (j=3) -> 32 frags = 128 regs
  bf16x8 Wr[8][4];
  #pragma unroll
  for (int f = 0; f < 8; f++){
    #pragma unroll
    for (int j = 0; j < 3; j++)
      Wr[f][j] = *(const bf16x8*)&wp[(((f >> 1)*16 + 2*w + (f & 1))*8 + j)*64 + l];
    Wr[f][3] = *(const bf16x8*)&wp[(((f >> 1)*16 + 2*w + (f & 1))*8 + 4)*64 + l];
  }
  __syncthreads();

  f32x4 c4[2] = {{0.f,0.f,0.f,0.f},{0.f,0.f,0.f,0.f}};

  // prologue: xz(0) -> acc (C-init); Wg <- kb3
  f32x4 acc[8];
  {
    const int tok0 = ts[l15][dir ? 127 : 0];
    const float* gp = ep + tok0*1024 + 32*w + lg*4;
    #pragma unroll
    for (int f = 0; f < 8; f++)
      acc[f] = *(const f32x4*)(gp + (f >> 1)*256 + (f & 1)*16);
  }
  bf16x8 Wg[8];
  #pragma unroll
  for (int f = 0; f < 8; f++) Wg[f] = *(const bf16x8*)&wsb[f*64];

#define MFMA8(AW, J, BB) \
  _Pragma("unroll") \
  for (int f = 0; f < 8; f++) \
    acc[f] = __builtin_amdgcn_mfma_f32_16x16x32_bf16(AW[f][J], BB, acc[f], 0, 0, 0);
#define MFMA8W(AW, BB) \
  _Pragma("unroll") \
  for (int f = 0; f < 8; f++) \
    acc[f] = __builtin_amdgcn_mfma_f32_16x16x32_bf16(AW[f], BB, acc[f], 0, 0, 0);

// fused-rcp gates: sig(i)*tanh(g) = (G-1)*rcp((1+2^-zi)(G+1)); h = (E-1)*rcp((E+1)(1+2^-zo))
#define GATES(Q, HN) { \
  f32x4 cn; \
  _Pragma("unroll") \
  for (int r = 0; r < 4; r++){ \
    const float zi = acc[0+(Q)][r], zf = acc[2+(Q)][r], zg = acc[4+(Q)][r], zo = acc[6+(Q)][r]; \
    const float G  = __builtin_amdgcn_exp2f(zg); \
    const float sf = __builtin_amdgcn_rcpf(1.f + __builtin_amdgcn_exp2f(-zf)); \
    const float it = (G - 1.f) * __builtin_amdgcn_rcpf((1.f + __builtin_amdgcn_exp2f(-zi))*(G + 1.f)); \
    const float cc = sf*c4[Q][r] + it; \
    const float E  = __builtin_amdgcn_exp2f(LOG2E2*cc); \
    HN[r] = (E - 1.f) * __builtin_amdgcn_rcpf((E + 1.f)*(1.f + __builtin_amdgcn_exp2f(-zo))); \
    cn[r] = cc; \
  } \
  c4[Q] = cn; }

  f32x4 hn0, hn1;

  for (int t = 0; t < 128; t++){
    const int tn    = (t < 127) ? t + 1 : 127;
    const int tok_n = ts[l15][dir ? (127 - tn) : tn];
    const int rb = t & 1;

    bf16x8 B0 = *(const bf16x8*)&hbuf[rb][0][l][0];
    bf16x8 B1 = *(const bf16x8*)&hbuf[rb][1][l][0];
    bf16x8 B2 = *(const bf16x8*)&hbuf[rb][2][l][0];
    __builtin_amdgcn_s_setprio(1);
    MFMA8(Wr, 0, B0);                         // kb0
    bf16x8 B3 = *(const bf16x8*)&hbuf[rb][3][l][0];
    MFMA8(Wr, 1, B1);                         // kb1
    bf16x8 B4 = *(const bf16x8*)&hbuf[rb][4][l][0];
    MFMA8(Wr, 2, B2);                         // kb2
    bf16x8 B6 = *(const bf16x8*)&hbuf[rb][6][l][0];
    MFMA8W(Wg, B3);                           // kb3 (streamed, loaded prev step)
    // refill window: kb5 (consumed ~5 groups below; L2-hot)
    #pragma unroll
    for (int f = 0; f < 8; f++) Wg[f] = *(const bf16x8*)&wsb[(8 + f)*64];
    bf16x8 B7 = *(const bf16x8*)&hbuf[rb][7][l][0];
    MFMA8(Wr, 3, B4);                         // kb4 (resident)
    bf16x8 B5 = *(const bf16x8*)&hbuf[rb][5][l][0];
    // kb6/kb7 from LDS, one 4-frag JIT window
    {
      bf16x8 Wl[4];
      #pragma unroll
      for (int j = 0; j < 4; j++) Wl[j] = *(const bf16x8*)&wlds[w][j][0][l];
      #pragma unroll
      for (int f = 0; f < 4; f++)
        acc[f] = __builtin_amdgcn_mfma_f32_16x16x32_bf16(Wl[f], B6, acc[f], 0, 0, 0);
      #pragma unroll
      for (int j = 0; j < 4; j++) Wl[j] = *(const bf16x8*)&wlds[w][4 + j][0][l];
      #pragma unroll
      for (int f = 4; f < 8; f++)
        acc[f] = __builtin_amdgcn_mfma_f32_16x16x32_bf16(Wl[f - 4], B6, acc[f], 0, 0, 0);
      #pragma unroll
      for (int j = 0; j < 4; j++) Wl[j] = *(const bf16x8*)&wlds[w][j][1][l];
      #pragma unroll
      for (int f = 0; f < 4; f++)
        acc[f] = __builtin_amdgcn_mfma_f32_16x16x32_bf16(Wl[f], B7, acc[f], 0, 0, 0);
      #pragma unroll
      for (int j = 0; j < 4; j++) Wl[j] = *(const bf16x8*)&wlds[w][4 + j][1][l];
      #pragma unroll
      for (int f = 4; f < 8; f++)
        acc[f] = __builtin_amdgcn_mfma_f32_16x16x32_bf16(Wl[f - 4], B7, acc[f], 0, 0, 0);
    }
    MFMA8W(Wg, B5);                           // kb5 (streamed)
    __builtin_amdgcn_s_setprio(0);

    // gates (read acc), then overwrite acc with xz(t+1)
    GATES(0, hn0);
    GATES(1, hn1);

    u32x4 pk;
    pk.x = cvt_pk_bf16(hn0[0], hn0[1]);
    pk.y = cvt_pk_bf16(hn0[2], hn0[3]);
    pk.z = cvt_pk_bf16(hn1[0], hn1[1]);
    pk.w = cvt_pk_bf16(hn1[2], hn1[3]);
    if (t == 127){
      const int b = r0 + l15;
      const int u0 = 32*w + lg*4;
      *(f32x4*)(out + b*512 + dir*256 + u0)                    = hn0;
      *(f32x4*)(out + b*512 + dir*256 + u0 + 16)               = hn1;
      *(f32x4*)(out + 1048576 + dir*1048576 + b*256 + u0)      = hn0;
      *(f32x4*)(out + 1048576 + dir*1048576 + b*256 + u0 + 16) = hn1;
    }
    *(u32x4*)&hbuf[rb ^ 1][w][l][0] = pk;

    // next step's stream window (kb3) + xz(t+1): in flight across the barrier
    #pragma unroll
    for (int f = 0; f < 8; f++) Wg[f] = *(const bf16x8*)&wsb[f*64];
    const float* gpn = ep + tok_n*1024 + 32*w + lg*4;
    #pragma unroll
    for (int f = 0; f < 8; f++)
      acc[f] = *(const f32x4*)(gpn + (f >> 1)*256 + (f & 1)*16);

    asm volatile("s_waitcnt lgkmcnt(0)" ::: "memory");
    __builtin_amdgcn_s_barrier();
    __builtin_amdgcn_sched_barrier(0);
  }

  #pragma unroll
  for (int q = 0; q < 2; q++){
    const int b  = r0 + l15;
    const int u0 = 32*w + 16*q + lg*4;
    *(f32x4*)(out + 1572864 + dir*1048576 + b*256 + u0) = c4[q];
  }
#undef MFMA8
#undef MFMA8W
#undef GATES
}

extern "C" void kernel_launch(void* const* d_in, const int* in_sizes, int n_in,
                              void* d_out, int out_size, void* d_ws, size_t ws_size,
                              hipStream_t stream){
  const int*   tokens = (const int*)  d_in[0];
  const float* emb    = (const float*)d_in[1];
  const float* Wx_f   = (const float*)d_in[2];
  const float* Wh_f   = (const float*)d_in[3];
  const float* b_f    = (const float*)d_in[4];
  const float* Wx_b   = (const float*)d_in[5];
  const float* Wh_b   = (const float*)d_in[6];
  const float* b_b    = (const float*)d_in[7];
  float* out = (float*)d_out;

  // ws: embproj 1 MB | whpack 1 MB | wstream 256 KB
  float*  embproj = (float*)d_ws;
  u32x4*  whpack  = (u32x4*)(embproj + 262144);
  u32x4*  wstream = whpack + 65536;

  embproj_kernel<<<1024, 256, 0, stream>>>(emb, Wx_f, b_f, Wx_b, b_b, embproj);
  whpack_kernel<<<256, 256, 0, stream>>>(Wh_f, Wh_b, whpack);
  wstream_kernel<<<64, 256, 0, stream>>>(whpack, wstream);
  lstm_kernel<<<256, 512, 0, stream>>>(tokens, embproj, whpack, wstream, out);
}

// Round 11
// 481.845 us; speedup vs baseline: 1.2444x; 1.0005x over previous
//
#include <hip/hip_runtime.h>

typedef __attribute__((ext_vector_type(8))) short bf16x8;
typedef __attribute__((ext_vector_type(4))) float f32x4;
typedef __attribute__((ext_vector_type(2))) unsigned int u32x2;
typedef __attribute__((ext_vector_type(4))) unsigned int u32x4;

#define LOG2E  1.442695040888963f
#define LOG2E2 2.885390081777927f

__device__ __forceinline__ unsigned cvt_pk_bf16(float lo, float hi){
  unsigned r; asm("v_cvt_pk_bf16_f32 %0, %1, %2" : "=v"(r) : "v"(lo), "v"(hi)); return r;
}

// ---------------- prologue 1: embproj[dir][tok][m] = (emb[tok]@Wx + b) * gate_scale ------
__global__ void embproj_kernel(const float* __restrict__ emb,
                               const float* __restrict__ Wx_f, const float* __restrict__ b_f,
                               const float* __restrict__ Wx_b, const float* __restrict__ b_b,
                               float* __restrict__ embproj){
  const int blk = blockIdx.x;
  const int dir = blk >> 9;
  const int tok = (blk >> 2) & 127;
  const int m   = (blk & 3)*256 + threadIdx.x;
  const float* Wx = dir ? Wx_b : Wx_f;
  const float* bb = dir ? b_b  : b_f;
  __shared__ float es[128];
  if (threadIdx.x < 128) es[threadIdx.x] = emb[tok*128 + threadIdx.x];
  __syncthreads();
  float acc = bb[m];
  #pragma unroll 4
  for (int e = 0; e < 128; e++) acc = fmaf(es[e], Wx[e*1024 + m], acc);
  const float s = ((m >> 8) == 2) ? LOG2E2 : LOG2E;
  embproj[(dir*128 + tok)*1024 + m] = acc * s;
}

// ---------------- prologue 2: pack Wh^T into MFMA A-frag order (bf16), pre-scaled ---------
// frag layout: [dir][mf(64)][kb(8)][lane(64)] x 16B; m = mf*16+(l&15),
// k-slot j: k = kb*32 + (l>>4)*4 + (j&3) + 16*(j>>2)   (A and B share the map)
__global__ void whpack_kernel(const float* __restrict__ Wh_f, const float* __restrict__ Wh_b,
                              u32x4* __restrict__ whpack){
  const int t = blockIdx.x*256 + threadIdx.x;
  const int lane = t & 63;
  const int kb   = (t >> 6) & 7;
  const int mf   = (t >> 9) & 63;
  const int dir  = t >> 15;
  const float* Wh = dir ? Wh_b : Wh_f;
  const int m = mf*16 + (lane & 15);
  const int kbase = kb*32 + ((lane >> 4) << 2);
  const float s = ((mf >> 4) == 2) ? LOG2E2 : LOG2E;
  u32x4 o;
  #pragma unroll
  for (int p = 0; p < 4; p++){
    const int k0 = kbase + (p & 1)*2 + (p >> 1)*16;
    unsigned pk = cvt_pk_bf16(Wh[k0*1024 + m]*s, Wh[(k0+1)*1024 + m]*s);
    if (p == 0) o.x = pk; else if (p == 1) o.y = pk; else if (p == 2) o.z = pk; else o.w = pk;
  }
  whpack[t] = o;
}

// ---------------- prologue 3: repack streamed frags (kb4,kb5) contiguous per wave ---------
// wstream[dir][w(16)][s(2)][g(4)][lane]: loop-invariant base + const offsets in main loop.
__global__ void wstream_kernel(const u32x4* __restrict__ whpack, u32x4* __restrict__ wstream){
  const int t = blockIdx.x*256 + threadIdx.x;   // 16384
  const int lane = t & 63;
  const int g    = (t >> 6) & 3;
  const int s    = (t >> 8) & 1;
  const int w    = (t >> 9) & 15;
  const int dir  = t >> 13;
  const int mf = g*16 + w;
  const int kb = s ? 5 : 4;
  wstream[t] = whpack[dir*32768 + (mf*8 + kb)*64 + lane];
}

// ---------------- main: persistent LSTM, 16 waves (4/SIMD) --------------------------------
// grid 256 = 2 dir * 128 tiles of 16 batch rows. 1024 thr = 16 waves = 4/SIMD (128-reg cap).
// Wave w owns units [16w,16w+16): frag g (gate) -> mf = g*16 + w.
//   kb0..3 resident Wr (16 frags = 64 regs — FITS the cap, unlike r3/r8 pressure disasters)
//   kb4,kb5 streamed via one 4-frag window Wg (wstream, const offsets)
//   kb6,kb7 in LDS (128 KB), 4-frag JIT window
// 4 waves/SIMD is the latency-hiding the 2-wave config lacked; no setprio (r10 regression).
// Barrier drains lgkm only; Wg refill + xz(t+1) stay in flight across it.
__global__ __launch_bounds__(1024, 4) void lstm_kernel(
    const int* __restrict__ tokens, const float* __restrict__ embproj,
    const u32x4* __restrict__ whpack, const u32x4* __restrict__ wstream,
    float* __restrict__ out)
{
  const int bid = blockIdx.x;
  const int dir = bid >> 7;
  const int r0  = (bid & 127) << 4;
  const int tid = threadIdx.x;
  const int w   = tid >> 6;     // 0..15
  const int l   = tid & 63;
  const int l15 = l & 15;
  const int lg  = l >> 4;

  const float* ep  = embproj + dir*131072;
  const u32x4* wp  = whpack + dir*32768;
  const u32x4* wsb = wstream + ((dir*16 + w)*8)*64 + l;   // loop-invariant stream base

  __shared__ __align__(16) unsigned hbuf[2][8][64][4];    // 16 KB h double-buffer (B-frag)
  __shared__ __align__(16) u32x4 wlds[16][4][2][64];      // 128 KB: [w][g][kb-6][lane]
  __shared__ int ts[16][132];                             // 8.25 KB tokens (padded)

  for (int i = tid; i < 2048; i += 1024)
    ts[i >> 7][i & 127] = tokens[(r0 + (i >> 7))*128 + (i & 127)];
  for (int i = tid; i < 4096; i += 1024) (&hbuf[0][0][0][0])[i] = 0u;
  #pragma unroll
  for (int g = 0; g < 4; g++)
    #pragma unroll
    for (int kbh = 0; kbh < 2; kbh++)
      wlds[w][g][kbh][l] = wp[((g*16 + w)*8 + 6 + kbh)*64 + l];

  // resident: kb0..3 -> 16 frags = 64 regs
  bf16x8 Wr[4][4];
  #pragma unroll
  for (int g = 0; g < 4; g++)
    #pragma unroll
    for (int j = 0; j < 4; j++)
      Wr[g][j] = *(const bf16x8*)&wp[((g*16 + w)*8 + j)*64 + l];
  __syncthreads();

  f32x4 c4 = {0.f,0.f,0.f,0.f};   // c for (b=r0+l15, u=16w+lg*4+r)

  // prologue: xz(0) -> acc (C-init); Wg <- kb4
  f32x4 acc[4];
  {
    const int tok0 = ts[l15][dir ? 127 : 0];
    const float* gp = ep + tok0*1024 + 16*w + lg*4;
    #pragma unroll
    for (int g = 0; g < 4; g++) acc[g] = *(const f32x4*)(gp + g*256);
  }
  bf16x8 Wg[4];
  #pragma unroll
  for (int g = 0; g < 4; g++) Wg[g] = *(const bf16x8*)&wsb[g*64];

#define MFMA4R(J, BB) \
  _Pragma("unroll") \
  for (int g = 0; g < 4; g++) \
    acc[g] = __builtin_amdgcn_mfma_f32_16x16x32_bf16(Wr[g][J], BB, acc[g], 0, 0, 0);
#define MFMA4W(AW, BB) \
  _Pragma("unroll") \
  for (int g = 0; g < 4; g++) \
    acc[g] = __builtin_amdgcn_mfma_f32_16x16x32_bf16(AW[g], BB, acc[g], 0, 0, 0);

  f32x4 hn;

  for (int t = 0; t < 128; t++){
    const int tn    = (t < 127) ? t + 1 : 127;
    const int tok_n = ts[l15][dir ? (127 - tn) : tn];
    const int rb = t & 1;

    bf16x8 B0 = *(const bf16x8*)&hbuf[rb][0][l][0];
    bf16x8 B1 = *(const bf16x8*)&hbuf[rb][1][l][0];
    MFMA4R(0, B0);                               // kb0
    bf16x8 B2 = *(const bf16x8*)&hbuf[rb][2][l][0];
    MFMA4R(1, B1);                               // kb1
    bf16x8 B3 = *(const bf16x8*)&hbuf[rb][3][l][0];
    MFMA4R(2, B2);                               // kb2
    bf16x8 B4 = *(const bf16x8*)&hbuf[rb][4][l][0];
    MFMA4R(3, B3);                               // kb3
    bf16x8 B5 = *(const bf16x8*)&hbuf[rb][5][l][0];
    MFMA4W(Wg, B4);                              // kb4 (streamed, preloaded)
    // refill window: kb5 (consumed after kb6/kb7 -> ~8 MFMAs + 8 ds of cover)
    #pragma unroll
    for (int g = 0; g < 4; g++) Wg[g] = *(const bf16x8*)&wsb[(4 + g)*64];

    bf16x8 B6 = *(const bf16x8*)&hbuf[rb][6][l][0];
    {
      bf16x8 Wl[4];
      #pragma unroll
      for (int g = 0; g < 4; g++) Wl[g] = *(const bf16x8*)&wlds[w][g][0][l];
      MFMA4W(Wl, B6);                            // kb6 (LDS)
      bf16x8 B7 = *(const bf16x8*)&hbuf[rb][7][l][0];
      #pragma unroll
      for (int g = 0; g < 4; g++) Wl[g] = *(const bf16x8*)&wlds[w][g][1][l];
      MFMA4W(Wl, B7);                            // kb7 (LDS)
    }
    MFMA4W(Wg, B5);                              // kb5 (streamed)

    // gates (fused-rcp): sig(i)*tanh(g) = (G-1)*rcp((1+2^-zi)(G+1));
    //                    h = (E-1)*rcp((E+1)(1+2^-zo)),  E = 2^(2*log2e*c)
    {
      f32x4 cn;
      #pragma unroll
      for (int r = 0; r < 4; r++){
        const float zi = acc[0][r], zf = acc[1][r], zg = acc[2][r], zo = acc[3][r];
        const float G  = __builtin_amdgcn_exp2f(zg);
        const float sf = __builtin_amdgcn_rcpf(1.f + __builtin_amdgcn_exp2f(-zf));
        const float it = (G - 1.f) * __builtin_amdgcn_rcpf((1.f + __builtin_amdgcn_exp2f(-zi))*(G + 1.f));
        const float cc = sf*c4[r] + it;
        const float E  = __builtin_amdgcn_exp2f(LOG2E2*cc);
        hn[r] = (E - 1.f) * __builtin_amdgcn_rcpf((E + 1.f)*(1.f + __builtin_amdgcn_exp2f(-zo)));
        cn[r] = cc;
      }
      c4 = cn;
    }

    u32x2 pk;
    pk.x = cvt_pk_bf16(hn[0], hn[1]);
    pk.y = cvt_pk_bf16(hn[2], hn[3]);
    if (t == 127){
      const int b  = r0 + l15;
      const int u0 = 16*w + lg*4;
      *(f32x4*)(out + b*512 + dir*256 + u0)               = hn;
      *(f32x4*)(out + 1048576 + dir*1048576 + b*256 + u0) = hn;
    }
    // h (bf16) -> next buffer: wave w's units are frag kb=w>>1, words (w&1)*2..+1
    *(u32x2*)&hbuf[rb ^ 1][w >> 1][l][(w & 1)*2] = pk;

    // next step's stream window (kb4) + xz(t+1): in flight across the barrier
    #pragma unroll
    for (int g = 0; g < 4; g++) Wg[g] = *(const bf16x8*)&wsb[g*64];
    const float* gpn = ep + tok_n*1024 + 16*w + lg*4;
    #pragma unroll
    for (int g = 0; g < 4; g++) acc[g] = *(const f32x4*)(gpn + g*256);

    asm volatile("s_waitcnt lgkmcnt(0)" ::: "memory");
    __builtin_amdgcn_s_barrier();
    __builtin_amdgcn_sched_barrier(0);
  }

  {
    const int b  = r0 + l15;
    const int u0 = 16*w + lg*4;
    *(f32x4*)(out + 1572864 + dir*1048576 + b*256 + u0) = c4;
  }
#undef MFMA4R
#undef MFMA4W
}

extern "C" void kernel_launch(void* const* d_in, const int* in_sizes, int n_in,
                              void* d_out, int out_size, void* d_ws, size_t ws_size,
                              hipStream_t stream){
  const int*   tokens = (const int*)  d_in[0];
  const float* emb    = (const float*)d_in[1];
  const float* Wx_f   = (const float*)d_in[2];
  const float* Wh_f   = (const float*)d_in[3];
  const float* b_f    = (const float*)d_in[4];
  const float* Wx_b   = (const float*)d_in[5];
  const float* Wh_b   = (const float*)d_in[6];
  const float* b_b    = (const float*)d_in[7];
  float* out = (float*)d_out;

  // ws: embproj 1 MB | whpack 1 MB | wstream 256 KB
  float*  embproj = (float*)d_ws;
  u32x4*  whpack  = (u32x4*)(embproj + 262144);
  u32x4*  wstream = whpack + 65536;

  embproj_kernel<<<1024, 256, 0, stream>>>(emb, Wx_f, b_f, Wx_b, b_b, embproj);
  whpack_kernel<<<256, 256, 0, stream>>>(Wh_f, Wh_b, whpack);
  wstream_kernel<<<64, 256, 0, stream>>>(whpack, wstream);
  lstm_kernel<<<256, 1024, 0, stream>>>(tokens, embproj, whpack, wstream, out);
}